// Round 15
// baseline (355.053 us; speedup 1.0000x reference)
//
#include <hip/hip_runtime.h>
#include <hip/hip_cooperative_groups.h>

namespace cg = cooperative_groups;

#define NPIX 16384   // 128*128
#define NN   256     // max_nodes
#define CC   256     // NFEAT
#define HH   128     // SCORER_HIDDEN
#define EE   65280   // NN*(NN-1)
#define BB   4
#define NG   16      // histogram privatization groups (per wave)

typedef __attribute__((ext_vector_type(8))) short short8;   // bf16x8 MFMA frag
typedef __attribute__((ext_vector_type(4))) float f32x4;    // fp32x4 acc

__device__ __forceinline__ unsigned short f2bf(float f){
  unsigned b = __float_as_uint(f);
  return (unsigned short)((b + 0x7fffu + ((b >> 16) & 1u)) >> 16);
}
__device__ __forceinline__ float bf2f(unsigned short s){ return __uint_as_float(((unsigned)s) << 16); }

// ---------------- Kernel 1: top-k (blocks 0..3) + weight bf16 transpose (blocks 4..451) ----
__global__ __launch_bounds__(1024) void k_topk(
    const float* __restrict__ jl, const float* __restrict__ off,
    int* __restrict__ topi, int* __restrict__ valid, float* __restrict__ inv_deg,
    float* __restrict__ out_nodes, float* __restrict__ Sbuf,
    const float* __restrict__ Wself, const float* __restrict__ Wnbr,
    const float* __restrict__ Ws1,
    unsigned short* __restrict__ wbfT, unsigned short* __restrict__ wuvT)
{
  __shared__ int hist[NG][257];
  __shared__ int histT[256];
  __shared__ unsigned long long s_sel[NN];
  __shared__ unsigned long long s_T;
  __shared__ int s_digit, s_krem, s_cnt, s_vcnt, s_break;
  __shared__ float tile[32][33];

  const int bid = blockIdx.x;
  const int tid = threadIdx.x;

  if (bid >= BB) {
    const int blk = bid - BB;            // 0..447
    const int m = blk >> 6;              // 0..6
    const int t = blk & 63;
    const int r  = tid >> 5;             // 0..31
    const int cl = tid & 31;
    if (m < 6) {
      const int tr = t >> 3, tc = t & 7;
      const float* src = (m < 3) ? (Wself + (size_t)m*65536) : (Wnbr + (size_t)(m-3)*65536);
      tile[r][cl] = src[(size_t)(tr*32 + r)*256 + tc*32 + cl];
      __syncthreads();
      wbfT[(size_t)m*65536 + (size_t)(tc*32 + r)*256 + tr*32 + cl] = f2bf(tile[cl][r]);
    } else {
      const int tr = t >> 2, tc = t & 3;   // tr 0..15 (512 rows), tc 0..3 (128 cols)
      tile[r][cl] = Ws1[(size_t)(tr*32 + r)*128 + tc*32 + cl];
      __syncthreads();
      int h  = tc*32 + r;          // 0..127
      int cgx = tr*32 + cl;        // 0..511
      int col = h + ((cgx >= 256) ? 128 : 0);
      wuvT[(size_t)col*256 + (cgx & 255)] = f2bf(tile[cl][r]);
    }
    return;
  }

  const int b = bid;
  const int grp = tid >> 6;            // one private hist per wave
  if (tid == 0) { s_cnt = 0; s_vcnt = 0; }

  {
    int l = tid >> 8, c = tid & 255;
    Sbuf[l*BB*CC + b*CC + c] = 0.0f;
  }

  unsigned long long rk[16];
  const float* p = jl + (size_t)b * NPIX;
  #pragma unroll
  for (int r = 0; r < 16; ++r) {
    int i = tid + (r << 10);
    float x = p[i];
    float pr = 1.0f / (1.0f + expf(-x));
    unsigned bits = __float_as_uint(pr);
    rk[r] = ((unsigned long long)bits << 32) | (unsigned)(0xFFFFFFFFu - (unsigned)i);
  }

  unsigned long long prefix = 0;
  int k = NN;
  int shift = 56;
  int brk = 0;
  for (int pass = 0; pass < 8 && !brk; ++pass) {
    shift = 56 - 8 * pass;
    for (int i = tid; i < NG * 257; i += 1024) ((int*)hist)[i] = 0;
    __syncthreads();
    unsigned long long pmask = (pass == 0) ? 0ULL : (~0ULL << (shift + 8));
    #pragma unroll
    for (int r = 0; r < 16; ++r) {
      unsigned long long kk = rk[r];
      if ((kk & pmask) == prefix)
        atomicAdd(&hist[grp][(int)((kk >> shift) & 255)], 1);
    }
    __syncthreads();
    if (tid < 256) {
      int t = 0;
      #pragma unroll
      for (int g = 0; g < NG; ++g) t += hist[g][tid];
      histT[tid] = t;
    }
    __syncthreads();
    if (tid < 64) {
      int h0 = histT[4*tid + 0], h1 = histT[4*tid + 1];
      int h2 = histT[4*tid + 2], h3 = histT[4*tid + 3];
      int tot = h0 + h1 + h2 + h3;
      int suf = tot;
      #pragma unroll
      for (int d = 1; d < 64; d <<= 1) {
        int o = __shfl_down(suf, d);
        if (tid + d < 64) suf += o;
      }
      int above = suf - tot;
      int c3 = h3 + above;
      int c2 = c3 + h2;
      int c1 = c2 + h1;
      int c0 = c1 + h0;
      if      (c3 >= k && above < k) { s_digit = 4*tid+3; s_krem = k - above; s_break = (h3 == 1); }
      else if (c2 >= k && c3    < k) { s_digit = 4*tid+2; s_krem = k - c3;    s_break = (h2 == 1); }
      else if (c1 >= k && c2    < k) { s_digit = 4*tid+1; s_krem = k - c2;    s_break = (h1 == 1); }
      else if (c0 >= k && c1    < k) { s_digit = 4*tid+0; s_krem = k - c1;    s_break = (h0 == 1); }
    }
    __syncthreads();
    prefix |= ((unsigned long long)s_digit) << shift;
    k = s_krem;
    brk = s_break;
  }

  if (shift == 0) {
    if (tid == 0) s_T = prefix;
  } else {
    unsigned long long known_mask = ~0ULL << shift;
    #pragma unroll
    for (int r = 0; r < 16; ++r)
      if ((rk[r] & known_mask) == prefix) s_T = rk[r];
  }
  __syncthreads();
  unsigned long long T = s_T;

  #pragma unroll
  for (int r = 0; r < 16; ++r) {
    unsigned long long kk = rk[r];
    if (kk >= T) { int pos = atomicAdd(&s_cnt, 1); s_sel[pos] = kk; }
  }
  __syncthreads();

  int my_rank = -1, my_v = 0;
  if (tid < NN) {
    unsigned long long mine = s_sel[tid];
    int rank = 0;
    #pragma unroll 16
    for (int j = 0; j < NN; ++j) rank += (s_sel[j] > mine) ? 1 : 0;
    unsigned bits = (unsigned)(mine >> 32);
    int v = bits > 0x3F000000u ? 1 : 0;
    int idx = (int)(0xFFFFFFFFu - (unsigned)(mine & 0xFFFFFFFFull));
    if (v) atomicAdd(&s_vcnt, 1);
    topi[b*NN + rank] = idx;
    valid[b*NN + rank] = v;
    int iy = idx >> 7;
    int ix = idx & 127;
    float yo = off[((size_t)b*2 + 0) * NPIX + idx];
    float xo = off[((size_t)b*2 + 1) * NPIX + idx];
    out_nodes[(b*NN + rank)*2 + 0] = ((float)ix + 0.5f + xo) * 4.0f;
    out_nodes[(b*NN + rank)*2 + 1] = ((float)iy + 0.5f + yo) * 4.0f;
    my_rank = rank; my_v = v;
  }
  __syncthreads();
  if (tid < NN) {
    int V = s_vcnt;
    inv_deg[b*NN + my_rank] = (my_v && V >= 2) ? 1.0f / (float)(V - 1) : 0.0f;
  }
}

// ================= Fused cooperative back half =================
// 512 blocks x 256 threads. Stages: gather -> gnn x3 -> uv -> edges,
// separated by grid.sync() instead of dispatch boundaries.

__device__ __forceinline__ void gnn_block(
    int bid, const unsigned short* __restrict__ x, const float* __restrict__ S,
    const float* __restrict__ inv_deg, const int* __restrict__ valid,
    const unsigned short* __restrict__ wT1, const unsigned short* __restrict__ wT2,
    const float* __restrict__ bias, unsigned short* __restrict__ xout,
    float* __restrict__ Snext, float* __restrict__ out_emb, float* smem)
{
  float* sA1 = smem;           // [16][33]
  float* sA2 = smem + 528;     // [16][33]
  float* sP2p = smem + 1056;   // [8][33]
  float* sP2 = smem + 1320;    // [32]
  const int mt = bid >> 3;
  const int cgx = bid & 7;
  const int row0 = mt * 16;
  const int b = row0 >> 8;
  const int tid = threadIdx.x;
  const int wave = tid >> 6;
  const int lane = tid & 63;

  // P2 slice
  {
    const int cl = tid >> 3;
    const int kw = tid & 7;
    const unsigned short* wrow = wT2 + (size_t)(cgx*32 + cl)*256 + kw*32;
    const float* Sb = S + b*CC + kw*32;
    float a = 0.f;
    #pragma unroll 8
    for (int i = 0; i < 32; ++i) a += Sb[i] * bf2f(wrow[i]);
    sP2p[kw*33 + cl] = a;
  }
  __syncthreads();
  if (tid < 32) {
    float s = 0.f;
    #pragma unroll
    for (int g = 0; g < 8; ++g) s += sP2p[g*33 + tid];
    sP2[tid] = s;
  }

  // MFMA GEMM
  const unsigned short* wT = (wave < 2) ? wT1 : wT2;
  const int colbase = cgx*32 + (wave & 1)*16;
  const int arow = row0 + (lane & 15);
  const int koff = (lane >> 4) * 8;
  const short8* aptr = (const short8*)(x + (size_t)arow*256 + koff);
  const short8* bptr = (const short8*)(wT + (size_t)(colbase + (lane & 15))*256 + koff);
  f32x4 acc = {0.f, 0.f, 0.f, 0.f};
  #pragma unroll
  for (int kk = 0; kk < 8; ++kk)
    acc = __builtin_amdgcn_mfma_f32_16x16x32_bf16(aptr[kk*4], bptr[kk*4], acc, 0, 0, 0);

  {
    float* dst = (wave < 2) ? sA1 : sA2;
    int ccol = (wave & 1)*16 + (lane & 15);
    #pragma unroll
    for (int r = 0; r < 4; ++r) {
      int crow = (lane >> 4)*4 + r;
      dst[crow*33 + ccol] = acc[r];
    }
  }
  __syncthreads();

  const int row = tid >> 4;
  const int cp2 = tid & 15;
  const int gr = row0 + row;
  const int c0 = cgx*32 + 2*cp2;
  float inv = inv_deg[gr];
  int   va  = valid[gr];
  float a10 = sA1[row*33 + 2*cp2], a11 = sA1[row*33 + 2*cp2+1];
  float a20 = sA2[row*33 + 2*cp2], a21 = sA2[row*33 + 2*cp2+1];
  float p0 = sP2[2*cp2], p1 = sP2[2*cp2+1];
  float o0 = fmaxf(a10 + inv*(p0 - a20) + bias[c0],     0.f); o0 = va ? o0 : 0.f;
  float o1 = fmaxf(a11 + inv*(p1 - a21) + bias[c0 + 1], 0.f); o1 = va ? o1 : 0.f;

  unsigned short h0 = f2bf(o0), h1 = f2bf(o1);
  ((unsigned*)xout)[(size_t)gr*128 + (cgx*16 + cp2)] = (unsigned)h0 | ((unsigned)h1 << 16);
  if (out_emb) {
    float2 v; v.x = o0; v.y = o1;
    *(float2*)&out_emb[(size_t)gr*CC + c0] = v;
  }
  if (Snext) {
    __syncthreads();
    sA1[row*33 + 2*cp2]   = bf2f(h0);
    sA1[row*33 + 2*cp2+1] = bf2f(h1);
    __syncthreads();
    if (tid < 32) {
      float s = 0.f;
      #pragma unroll
      for (int r = 0; r < 16; ++r) s += sA1[r*33 + tid];
      if (s != 0.f) atomicAdd(&Snext[b*CC + cgx*32 + tid], s);
    }
  }
}

__device__ __forceinline__ void uv_block(
    int bid, const unsigned short* __restrict__ x, const unsigned short* __restrict__ wuvT,
    const float* __restrict__ bs1, float* __restrict__ u, float* __restrict__ vt)
{
  const int mt = bid >> 2;
  const int cgx = bid & 3;
  const int row0 = mt * 16;
  const int b = row0 >> 8;
  const int wave = threadIdx.x >> 6;
  const int lane = threadIdx.x & 63;
  const int col = cgx*64 + wave*16 + (lane & 15);
  const int arow = row0 + (lane & 15);
  const int koff = (lane >> 4) * 8;
  const short8* aptr = (const short8*)(x + (size_t)arow*256 + koff);
  const short8* bptr = (const short8*)(wuvT + (size_t)col*256 + koff);
  f32x4 acc = {0.f, 0.f, 0.f, 0.f};
  #pragma unroll
  for (int kk = 0; kk < 8; ++kk)
    acc = __builtin_amdgcn_mfma_f32_16x16x32_bf16(aptr[kk*4], bptr[kk*4], acc, 0, 0, 0);
  const int rbase = row0 + (lane >> 4)*4;
  if (col < HH) {
    float bv = bs1[col];
    #pragma unroll
    for (int r = 0; r < 4; ++r)
      u[(size_t)(rbase + r)*HH + col] = acc[r] + bv;
  } else {
    float4 v; v.x = acc[0]; v.y = acc[1]; v.z = acc[2]; v.w = acc[3];
    *(float4*)&vt[(size_t)(b*HH + (col - HH))*NN + rbase] = v;
  }
}

__device__ __forceinline__ void edges_unit(
    int unit, const float* __restrict__ u, const float* __restrict__ vt,
    const float* __restrict__ Ws2, const float* __restrict__ bs2,
    const int* __restrict__ valid,
    float* __restrict__ out_logits, float* __restrict__ out_keep, float* smem)
{
  float4* red = (float4*)smem;        // [3][64]
  const int b = unit >> 8;
  const int i = unit & 255;
  const int tid = threadIdx.x;
  const int jq = tid & 63;
  const int kh = tid >> 6;
  const float* urow = u + ((size_t)(b*NN + i))*HH + kh*32;
  const float* wrow = Ws2 + kh*32;
  const float4* vbase = (const float4*)(vt + (size_t)(b*HH + kh*32)*NN) + jq;
  float ax = 0.f, ay = 0.f, az = 0.f, aw = 0.f;
  #pragma unroll 8
  for (int h = 0; h < 32; ++h) {
    float uh = urow[h];
    float wh = wrow[h];
    float4 v = vbase[(size_t)h*64];
    ax += fmaxf(uh + v.x, 0.f)*wh;
    ay += fmaxf(uh + v.y, 0.f)*wh;
    az += fmaxf(uh + v.z, 0.f)*wh;
    aw += fmaxf(uh + v.w, 0.f)*wh;
  }
  if (kh > 0) {
    float4 t; t.x = ax; t.y = ay; t.z = az; t.w = aw;
    red[(kh-1)*64 + jq] = t;
  }
  __syncthreads();
  if (kh == 0) {
    float4 r0 = red[jq], r1 = red[64 + jq], r2 = red[128 + jq];
    float bs = bs2[0];
    float lg0 = ax + r0.x + r1.x + r2.x + bs;
    float lg1 = ay + r0.y + r1.y + r2.y + bs;
    float lg2 = az + r0.z + r1.z + r2.z + bs;
    float lg3 = aw + r0.w + r1.w + r2.w + bs;
    int vi = valid[b*NN + i];
    float* Lb = out_logits + (size_t)b*EE;
    float* Kb = out_keep   + (size_t)b*EE;
    int j0 = 4*jq;
    {
      int j = j0;
      if (j != i) { int e = i*255 + (j < i ? j : j-1);
        Lb[e] = lg0; Kb[e] = (lg0 > 0.f && vi && valid[b*NN + j]) ? 1.0f : 0.0f; }
    }
    {
      int j = j0 + 1;
      if (j != i) { int e = i*255 + (j < i ? j : j-1);
        Lb[e] = lg1; Kb[e] = (lg1 > 0.f && vi && valid[b*NN + j]) ? 1.0f : 0.0f; }
    }
    {
      int j = j0 + 2;
      if (j != i) { int e = i*255 + (j < i ? j : j-1);
        Lb[e] = lg2; Kb[e] = (lg2 > 0.f && vi && valid[b*NN + j]) ? 1.0f : 0.0f; }
    }
    {
      int j = j0 + 3;
      if (j != i) { int e = i*255 + (j < i ? j : j-1);
        Lb[e] = lg3; Kb[e] = (lg3 > 0.f && vi && valid[b*NN + j]) ? 1.0f : 0.0f; }
    }
  }
}

__global__ __launch_bounds__(256, 2) void k_rest(
    const float* __restrict__ nmap, const int* __restrict__ topi,
    const int* __restrict__ valid, const float* __restrict__ inv_deg,
    float* __restrict__ Sbuf, unsigned short* __restrict__ xa,
    unsigned short* __restrict__ xb,
    const unsigned short* __restrict__ wbfT, const unsigned short* __restrict__ wuvT,
    const float* __restrict__ bg, const float* __restrict__ bs1,
    const float* __restrict__ Ws2, const float* __restrict__ bs2,
    float* __restrict__ u, float* __restrict__ vt,
    float* __restrict__ out_emb, float* __restrict__ out_logits,
    float* __restrict__ out_keep)
{
  __shared__ __align__(16) float smem[1360];
  cg::grid_group grid = cg::this_grid();
  const int tid = threadIdx.x;

  // ---- stage A: gather (2 rows per block) + colsum into Sbuf[0] ----
  #pragma unroll
  for (int r = 0; r < 2; ++r) {
    int bn = blockIdx.x*2 + r;
    int b = bn >> 8;
    int pix = topi[bn];
    int v = valid[bn];
    float val = v ? nmap[(((size_t)b*CC + tid) << 14) + pix] : 0.0f;
    unsigned short hb = f2bf(val);
    xa[(size_t)bn*CC + tid] = hb;
    float valr = bf2f(hb);
    if (valr != 0.0f) atomicAdd(&Sbuf[b*CC + tid], valr);
  }
  grid.sync();

  // ---- stages B-D: 3 GNN layers ----
  unsigned short* xc = xa; unsigned short* xn = xb;
  #pragma unroll
  for (int l = 0; l < 3; ++l) {
    gnn_block(blockIdx.x, xc, Sbuf + l*BB*CC, inv_deg, valid,
              wbfT + (size_t)l*65536, wbfT + (size_t)(3 + l)*65536, bg + l*CC,
              xn,
              (l < 2) ? (Sbuf + (l+1)*BB*CC) : (float*)nullptr,
              (l == 2) ? out_emb : (float*)nullptr,
              smem);
    grid.sync();
    unsigned short* t = xc; xc = xn; xn = t;
  }

  // ---- stage E: uv (blocks 0..255) ----
  if (blockIdx.x < 256)
    uv_block(blockIdx.x, xc, wuvT, bs1, u, vt);
  grid.sync();

  // ---- stage F: edges (2 units per block) ----
  edges_unit(blockIdx.x*2, u, vt, Ws2, bs2, valid, out_logits, out_keep, smem);
  __syncthreads();
  edges_unit(blockIdx.x*2 + 1, u, vt, Ws2, bs2, valid, out_logits, out_keep, smem);
}

extern "C" void kernel_launch(void* const* d_in, const int* in_sizes, int n_in,
                              void* d_out, int out_size, void* d_ws, size_t ws_size,
                              hipStream_t stream) {
  const float* jl    = (const float*)d_in[0];
  const float* off   = (const float*)d_in[1];
  const float* nmap  = (const float*)d_in[2];
  const float* Wself = (const float*)d_in[3];
  const float* Wnbr  = (const float*)d_in[4];
  const float* bg    = (const float*)d_in[5];
  const float* Ws1   = (const float*)d_in[6];
  const float* bs1   = (const float*)d_in[7];
  const float* Ws2   = (const float*)d_in[8];
  const float* bs2   = (const float*)d_in[9];

  char* ws = (char*)d_ws;
  int*   topi    = (int*)  (ws + 0);                 //  4 KiB
  int*   valid   = (int*)  (ws + 4096);              //  4 KiB
  float* inv_deg = (float*)(ws + 8192);              //  4 KiB
  float* Sbuf    = (float*)(ws + 12288);             // 16 KiB (layer colsums)
  unsigned short* xa = (unsigned short*)(ws + 28672);    // 512 KiB bf16
  unsigned short* xb = (unsigned short*)(ws + 552960);   // 512 KiB bf16
  float* u       = (float*)(ws + 1077248);           // 512 KiB fp32
  float* vt      = (float*)(ws + 1601536);           // 512 KiB fp32
  unsigned short* wbfT = (unsigned short*)(ws + 2125824); // 768 KiB transposed bf16
  unsigned short* wuvT = (unsigned short*)(ws + 2912256); // 128 KiB transposed bf16

  float* out        = (float*)d_out;
  float* out_nodes  = out;                  // [4,256,2]   -> 2048
  float* out_emb    = out + 2048;           // [4,256,256] -> 262144
  float* out_logits = out + 264192;         // [4,65280]   -> 261120
  float* out_keep   = out + 525312;         // [4,65280]   -> 261120

  hipLaunchKernelGGL(k_topk, dim3(BB + 448), dim3(1024), 0, stream,
                     jl, off, topi, valid, inv_deg, out_nodes, Sbuf,
                     Wself, Wnbr, Ws1, wbfT, wuvT);

  const int* topi_c  = topi;
  const int* valid_c = valid;
  const float* inv_c = inv_deg;
  const unsigned short* wbfT_c = wbfT;
  const unsigned short* wuvT_c = wuvT;
  void* kp[] = {
    (void*)&nmap, (void*)&topi_c, (void*)&valid_c, (void*)&inv_c,
    (void*)&Sbuf, (void*)&xa, (void*)&xb,
    (void*)&wbfT_c, (void*)&wuvT_c,
    (void*)&bg, (void*)&bs1, (void*)&Ws2, (void*)&bs2,
    (void*)&u, (void*)&vt,
    (void*)&out_emb, (void*)&out_logits, (void*)&out_keep
  };
  hipLaunchCooperativeKernel((void*)k_rest, dim3(512), dim3(256), kp, 0, stream);
}

// Round 16
// 76.915 us; speedup vs baseline: 4.6162x; 4.6162x over previous
//
#include <hip/hip_runtime.h>

#define NPIX 16384   // 128*128
#define NN   256     // max_nodes
#define CC   256     // NFEAT
#define HH   128     // SCORER_HIDDEN
#define EE   65280   // NN*(NN-1)
#define BB   4
#define NG   16      // histogram privatization groups (per wave)

typedef __attribute__((ext_vector_type(8))) short short8;   // bf16x8 MFMA frag
typedef __attribute__((ext_vector_type(4))) float f32x4;    // fp32x4 acc

__device__ __forceinline__ unsigned short f2bf(float f){
  unsigned b = __float_as_uint(f);
  return (unsigned short)((b + 0x7fffu + ((b >> 16) & 1u)) >> 16);
}
__device__ __forceinline__ float bf2f(unsigned short s){ return __uint_as_float(((unsigned)s) << 16); }

// ---------------- Kernel 1: top-k (blocks 0..3) + weight bf16 transpose (blocks 4..451) ----
__global__ __launch_bounds__(1024) void k_topk(
    const float* __restrict__ jl, const float* __restrict__ off,
    int* __restrict__ topi, int* __restrict__ valid, float* __restrict__ inv_deg,
    float* __restrict__ out_nodes, float* __restrict__ Sbuf,
    const float* __restrict__ Wself, const float* __restrict__ Wnbr,
    const float* __restrict__ Ws1,
    unsigned short* __restrict__ wbfT, unsigned short* __restrict__ wuvT)
{
  __shared__ int hist[NG][257];
  __shared__ int histT[256];
  __shared__ unsigned long long s_sel[NN];
  __shared__ unsigned long long s_T;
  __shared__ int s_digit, s_krem, s_cnt, s_vcnt, s_break;
  __shared__ float tile[32][33];

  const int bid = blockIdx.x;
  const int tid = threadIdx.x;

  if (bid >= BB) {
    const int blk = bid - BB;            // 0..447
    const int m = blk >> 6;              // 0..6
    const int t = blk & 63;
    const int r  = tid >> 5;             // 0..31
    const int cl = tid & 31;
    if (m < 6) {
      const int tr = t >> 3, tc = t & 7;
      const float* src = (m < 3) ? (Wself + (size_t)m*65536) : (Wnbr + (size_t)(m-3)*65536);
      tile[r][cl] = src[(size_t)(tr*32 + r)*256 + tc*32 + cl];
      __syncthreads();
      wbfT[(size_t)m*65536 + (size_t)(tc*32 + r)*256 + tr*32 + cl] = f2bf(tile[cl][r]);
    } else {
      const int tr = t >> 2, tc = t & 3;   // tr 0..15 (512 rows), tc 0..3 (128 cols)
      tile[r][cl] = Ws1[(size_t)(tr*32 + r)*128 + tc*32 + cl];
      __syncthreads();
      int h  = tc*32 + r;          // 0..127
      int cgx = tr*32 + cl;        // 0..511
      int col = h + ((cgx >= 256) ? 128 : 0);
      wuvT[(size_t)col*256 + (cgx & 255)] = f2bf(tile[cl][r]);
    }
    return;
  }

  const int b = bid;
  const int grp = tid >> 6;            // one private hist per wave
  if (tid == 0) { s_cnt = 0; s_vcnt = 0; }

  {
    int l = tid >> 8, c = tid & 255;
    Sbuf[l*BB*CC + b*CC + c] = 0.0f;
  }

  unsigned long long rk[16];
  const float* p = jl + (size_t)b * NPIX;
  #pragma unroll
  for (int r = 0; r < 16; ++r) {
    int i = tid + (r << 10);
    float x = p[i];
    float pr = 1.0f / (1.0f + expf(-x));
    unsigned bits = __float_as_uint(pr);
    rk[r] = ((unsigned long long)bits << 32) | (unsigned)(0xFFFFFFFFu - (unsigned)i);
  }

  unsigned long long prefix = 0;
  int k = NN;
  int shift = 56;
  int brk = 0;
  for (int pass = 0; pass < 8 && !brk; ++pass) {
    shift = 56 - 8 * pass;
    for (int i = tid; i < NG * 257; i += 1024) ((int*)hist)[i] = 0;
    __syncthreads();
    unsigned long long pmask = (pass == 0) ? 0ULL : (~0ULL << (shift + 8));
    #pragma unroll
    for (int r = 0; r < 16; ++r) {
      unsigned long long kk = rk[r];
      if ((kk & pmask) == prefix)
        atomicAdd(&hist[grp][(int)((kk >> shift) & 255)], 1);
    }
    __syncthreads();
    if (tid < 256) {
      int t = 0;
      #pragma unroll
      for (int g = 0; g < NG; ++g) t += hist[g][tid];
      histT[tid] = t;
    }
    __syncthreads();
    if (tid < 64) {
      int h0 = histT[4*tid + 0], h1 = histT[4*tid + 1];
      int h2 = histT[4*tid + 2], h3 = histT[4*tid + 3];
      int tot = h0 + h1 + h2 + h3;
      int suf = tot;
      #pragma unroll
      for (int d = 1; d < 64; d <<= 1) {
        int o = __shfl_down(suf, d);
        if (tid + d < 64) suf += o;
      }
      int above = suf - tot;
      int c3 = h3 + above;
      int c2 = c3 + h2;
      int c1 = c2 + h1;
      int c0 = c1 + h0;
      if      (c3 >= k && above < k) { s_digit = 4*tid+3; s_krem = k - above; s_break = (h3 == 1); }
      else if (c2 >= k && c3    < k) { s_digit = 4*tid+2; s_krem = k - c3;    s_break = (h2 == 1); }
      else if (c1 >= k && c2    < k) { s_digit = 4*tid+1; s_krem = k - c2;    s_break = (h1 == 1); }
      else if (c0 >= k && c1    < k) { s_digit = 4*tid+0; s_krem = k - c1;    s_break = (h0 == 1); }
    }
    __syncthreads();
    prefix |= ((unsigned long long)s_digit) << shift;
    k = s_krem;
    brk = s_break;
  }

  if (shift == 0) {
    if (tid == 0) s_T = prefix;
  } else {
    unsigned long long known_mask = ~0ULL << shift;
    #pragma unroll
    for (int r = 0; r < 16; ++r)
      if ((rk[r] & known_mask) == prefix) s_T = rk[r];
  }
  __syncthreads();
  unsigned long long T = s_T;

  #pragma unroll
  for (int r = 0; r < 16; ++r) {
    unsigned long long kk = rk[r];
    if (kk >= T) { int pos = atomicAdd(&s_cnt, 1); s_sel[pos] = kk; }
  }
  __syncthreads();

  int my_rank = -1, my_v = 0;
  if (tid < NN) {
    unsigned long long mine = s_sel[tid];
    int rank = 0;
    #pragma unroll 16
    for (int j = 0; j < NN; ++j) rank += (s_sel[j] > mine) ? 1 : 0;
    unsigned bits = (unsigned)(mine >> 32);
    int v = bits > 0x3F000000u ? 1 : 0;
    int idx = (int)(0xFFFFFFFFu - (unsigned)(mine & 0xFFFFFFFFull));
    if (v) atomicAdd(&s_vcnt, 1);
    topi[b*NN + rank] = idx;
    valid[b*NN + rank] = v;
    int iy = idx >> 7;
    int ix = idx & 127;
    float yo = off[((size_t)b*2 + 0) * NPIX + idx];
    float xo = off[((size_t)b*2 + 1) * NPIX + idx];
    out_nodes[(b*NN + rank)*2 + 0] = ((float)ix + 0.5f + xo) * 4.0f;
    out_nodes[(b*NN + rank)*2 + 1] = ((float)iy + 0.5f + yo) * 4.0f;
    my_rank = rank; my_v = v;
  }
  __syncthreads();
  if (tid < NN) {
    int V = s_vcnt;
    inv_deg[b*NN + my_rank] = (my_v && V >= 2) ? 1.0f / (float)(V - 1) : 0.0f;
  }
}

// ---------------- Kernel 2: gather node features (bf16 out) + fused colsum into S0 ----------------
__global__ __launch_bounds__(256) void k_gather(
    const float* __restrict__ nmap, const int* __restrict__ topi,
    const int* __restrict__ valid, unsigned short* __restrict__ x, float* __restrict__ S0)
{
  const int bn = blockIdx.x;
  const int b = bn >> 8;
  const int c = threadIdx.x;
  int pix = topi[bn];
  int v = valid[bn];
  float val = v ? nmap[(((size_t)b*CC + c) << 14) + pix] : 0.0f;
  unsigned short hb = f2bf(val);
  x[(size_t)bn*CC + c] = hb;
  float valr = bf2f(hb);
  if (valr != 0.0f) atomicAdd(&S0[b*CC + c], valr);
}

// ---------------- Kernel 3: GNN layer via MFMA, P2 fused in-block ----------------
__global__ __launch_bounds__(256) void k_gnn(
    const unsigned short* __restrict__ x, const float* __restrict__ S,
    const float* __restrict__ inv_deg, const int* __restrict__ valid,
    const unsigned short* __restrict__ wT1, const unsigned short* __restrict__ wT2,
    const float* __restrict__ bias, unsigned short* __restrict__ xout,
    float* __restrict__ Snext,     // may be null
    float* __restrict__ out_emb)   // may be null
{
  __shared__ float sA1[16][33];
  __shared__ float sA2[16][33];
  __shared__ float sP2p[8][33];
  __shared__ float sP2[32];
  const int mt = blockIdx.x >> 3;            // 0..63
  const int cg = blockIdx.x & 7;             // 0..7
  const int row0 = mt * 16;
  const int b = row0 >> 8;
  const int tid = threadIdx.x;
  const int wave = tid >> 6;
  const int lane = tid & 63;

  // ---- P2 slice: P2[cg*32 + cl] = sum_c S[c] * wT2[col][c] ----
  {
    const int cl = tid >> 3;         // 0..31
    const int kw = tid & 7;          // 0..7, 32 c's each
    const unsigned short* wrow = wT2 + (size_t)(cg*32 + cl)*256 + kw*32;
    const float* Sb = S + b*CC + kw*32;
    float a = 0.f;
    #pragma unroll 8
    for (int i = 0; i < 32; ++i) a += Sb[i] * bf2f(wrow[i]);
    sP2p[kw][cl] = a;
  }
  __syncthreads();
  if (tid < 32) {
    float s = 0.f;
    #pragma unroll
    for (int g = 0; g < 8; ++g) s += sP2p[g][tid];
    sP2[tid] = s;
  }

  // ---- MFMA GEMM ----
  const unsigned short* wT = (wave < 2) ? wT1 : wT2;
  const int colbase = cg*32 + (wave & 1)*16;
  const int arow = row0 + (lane & 15);
  const int koff = (lane >> 4) * 8;

  const short8* aptr = (const short8*)(x + (size_t)arow*256 + koff);
  const short8* bptr = (const short8*)(wT + (size_t)(colbase + (lane & 15))*256 + koff);

  f32x4 acc = {0.f, 0.f, 0.f, 0.f};
  #pragma unroll
  for (int kk = 0; kk < 8; ++kk) {
    short8 af = aptr[kk*4];      // advance 32 bf16 per chunk
    short8 bf = bptr[kk*4];
    acc = __builtin_amdgcn_mfma_f32_16x16x32_bf16(af, bf, acc, 0, 0, 0);
  }

  {
    float* dst = (wave < 2) ? &sA1[0][0] : &sA2[0][0];
    int ccol = (wave & 1)*16 + (lane & 15);
    #pragma unroll
    for (int r = 0; r < 4; ++r) {
      int crow = (lane >> 4)*4 + r;
      dst[crow*33 + ccol] = acc[r];
    }
  }
  __syncthreads();

  // epilogue: thread t -> row = t>>4, colpair cp2 = t&15
  const int row = tid >> 4;
  const int cp2 = tid & 15;
  const int gr = row0 + row;
  const int c0 = cg*32 + 2*cp2;
  float inv = inv_deg[gr];
  int   va  = valid[gr];
  float a10 = sA1[row][2*cp2], a11 = sA1[row][2*cp2+1];
  float a20 = sA2[row][2*cp2], a21 = sA2[row][2*cp2+1];
  float p0 = sP2[2*cp2], p1 = sP2[2*cp2+1];
  float o0 = fmaxf(a10 + inv*(p0 - a20) + bias[c0],     0.f); o0 = va ? o0 : 0.f;
  float o1 = fmaxf(a11 + inv*(p1 - a21) + bias[c0 + 1], 0.f); o1 = va ? o1 : 0.f;

  unsigned short h0 = f2bf(o0), h1 = f2bf(o1);
  ((unsigned*)xout)[(size_t)gr*128 + (cg*16 + cp2)] = (unsigned)h0 | ((unsigned)h1 << 16);
  if (out_emb) {
    float2 v; v.x = o0; v.y = o1;
    *(float2*)&out_emb[(size_t)gr*CC + c0] = v;
  }
  if (Snext) {
    __syncthreads();                 // all sA1 reads done
    sA1[row][2*cp2]   = bf2f(h0);    // colsum of rounded values (matches next layer's x)
    sA1[row][2*cp2+1] = bf2f(h1);
    __syncthreads();
    if (tid < 32) {
      float s = 0.f;
      #pragma unroll
      for (int r = 0; r < 16; ++r) s += sA1[r][tid];
      if (s != 0.f) atomicAdd(&Snext[b*CC + cg*32 + tid], s);
    }
  }
}

// ---------------- Kernel 4: u/vt via MFMA; bs1 folded into u ----------------
__global__ __launch_bounds__(256) void k_uv(
    const unsigned short* __restrict__ x, const unsigned short* __restrict__ wuvT,
    const float* __restrict__ bs1,
    float* __restrict__ u, float* __restrict__ vt)
{
  const int mt = blockIdx.x >> 2;      // 0..63
  const int cg = blockIdx.x & 3;       // 0..3 (64 cols each)
  const int row0 = mt * 16;
  const int b = row0 >> 8;
  const int wave = threadIdx.x >> 6;
  const int lane = threadIdx.x & 63;
  const int col = cg*64 + wave*16 + (lane & 15);
  const int arow = row0 + (lane & 15);
  const int koff = (lane >> 4) * 8;
  const short8* aptr = (const short8*)(x + (size_t)arow*256 + koff);
  const short8* bptr = (const short8*)(wuvT + (size_t)col*256 + koff);
  f32x4 acc = {0.f, 0.f, 0.f, 0.f};
  #pragma unroll
  for (int kk = 0; kk < 8; ++kk)
    acc = __builtin_amdgcn_mfma_f32_16x16x32_bf16(aptr[kk*4], bptr[kk*4], acc, 0, 0, 0);
  const int rbase = row0 + (lane >> 4)*4;
  if (col < HH) {
    float bv = bs1[col];
    #pragma unroll
    for (int r = 0; r < 4; ++r)
      u[(size_t)(rbase + r)*HH + col] = acc[r] + bv;
  } else {
    float4 v; v.x = acc[0]; v.y = acc[1]; v.z = acc[2]; v.w = acc[3];
    *(float4*)&vt[(size_t)(b*HH + (col - HH))*NN + rbase] = v;
  }
}

// ---------------- Kernel 5: per-edge scorer, 4 src nodes per block ----------------
// Block = (b, ig) where ig covers i = ig*4..ig*4+3. 256 thr = 4 h-partitions x 64 j-quads.
// vt float4 loaded once per (h,jq), reused for 4 src rows (4x less L2 traffic + instrs).
__global__ __launch_bounds__(256) void k_edges(
    const float* __restrict__ u, const float* __restrict__ vt,
    const float* __restrict__ Ws2, const float* __restrict__ bs2,
    const int* __restrict__ valid,
    float* __restrict__ out_logits, float* __restrict__ out_keep)
{
  __shared__ float su[4][HH];          // 2 KiB   u rows (bs1 already folded)
  __shared__ float sws[HH];            // 0.5 KiB Ws2
  __shared__ float4 red[3][4][64];     // 12 KiB  partial sums
  const int b  = blockIdx.x >> 6;
  const int ig = blockIdx.x & 63;
  const int i0 = ig * 4;
  const int tid = threadIdx.x;
  const int jq = tid & 63;
  const int kh = tid >> 6;             // h-partition 0..3 (32 h each)

  #pragma unroll
  for (int r = 0; r < 2; ++r) {
    int idx = tid + 256*r;             // 0..511
    int il = idx >> 7, h = idx & 127;
    su[il][h] = u[((size_t)(b*NN + i0 + il))*HH + h];
  }
  if (tid < HH) sws[tid] = Ws2[tid];
  __syncthreads();

  const float4* vbase = (const float4*)(vt + (size_t)(b*HH + kh*32)*NN) + jq;
  float4 acc0 = {0,0,0,0}, acc1 = {0,0,0,0}, acc2 = {0,0,0,0}, acc3 = {0,0,0,0};
  #pragma unroll 4
  for (int h = 0; h < 32; ++h) {
    float4 v = vbase[(size_t)h*64];
    float wh = sws[kh*32 + h];
    float u0 = su[0][kh*32 + h];
    float u1 = su[1][kh*32 + h];
    float u2 = su[2][kh*32 + h];
    float u3 = su[3][kh*32 + h];
    acc0.x += fmaxf(u0 + v.x, 0.f)*wh; acc0.y += fmaxf(u0 + v.y, 0.f)*wh;
    acc0.z += fmaxf(u0 + v.z, 0.f)*wh; acc0.w += fmaxf(u0 + v.w, 0.f)*wh;
    acc1.x += fmaxf(u1 + v.x, 0.f)*wh; acc1.y += fmaxf(u1 + v.y, 0.f)*wh;
    acc1.z += fmaxf(u1 + v.z, 0.f)*wh; acc1.w += fmaxf(u1 + v.w, 0.f)*wh;
    acc2.x += fmaxf(u2 + v.x, 0.f)*wh; acc2.y += fmaxf(u2 + v.y, 0.f)*wh;
    acc2.z += fmaxf(u2 + v.z, 0.f)*wh; acc2.w += fmaxf(u2 + v.w, 0.f)*wh;
    acc3.x += fmaxf(u3 + v.x, 0.f)*wh; acc3.y += fmaxf(u3 + v.y, 0.f)*wh;
    acc3.z += fmaxf(u3 + v.z, 0.f)*wh; acc3.w += fmaxf(u3 + v.w, 0.f)*wh;
  }
  if (kh > 0) {
    red[kh-1][0][jq] = acc0;
    red[kh-1][1][jq] = acc1;
    red[kh-1][2][jq] = acc2;
    red[kh-1][3][jq] = acc3;
  }
  __syncthreads();
  if (kh == 0) {
    float bs = bs2[0];
    float* Lb = out_logits + (size_t)b*EE;
    float* Kb = out_keep   + (size_t)b*EE;
    int j0 = 4*jq;
    int vj0 = valid[b*NN + j0 + 0];
    int vj1 = valid[b*NN + j0 + 1];
    int vj2 = valid[b*NN + j0 + 2];
    int vj3 = valid[b*NN + j0 + 3];
    #pragma unroll
    for (int il = 0; il < 4; ++il) {
      int i = i0 + il;
      int vi = valid[b*NN + i];
      float4 a = (il == 0) ? acc0 : (il == 1) ? acc1 : (il == 2) ? acc2 : acc3;
      float4 r0 = red[0][il][jq], r1 = red[1][il][jq], r2 = red[2][il][jq];
      float lg0 = a.x + r0.x + r1.x + r2.x + bs;
      float lg1 = a.y + r0.y + r1.y + r2.y + bs;
      float lg2 = a.z + r0.z + r1.z + r2.z + bs;
      float lg3 = a.w + r0.w + r1.w + r2.w + bs;
      {
        int j = j0;
        if (j != i) { int e = i*255 + (j < i ? j : j-1);
          Lb[e] = lg0; Kb[e] = (lg0 > 0.f && vi && vj0) ? 1.0f : 0.0f; }
      }
      {
        int j = j0 + 1;
        if (j != i) { int e = i*255 + (j < i ? j : j-1);
          Lb[e] = lg1; Kb[e] = (lg1 > 0.f && vi && vj1) ? 1.0f : 0.0f; }
      }
      {
        int j = j0 + 2;
        if (j != i) { int e = i*255 + (j < i ? j : j-1);
          Lb[e] = lg2; Kb[e] = (lg2 > 0.f && vi && vj2) ? 1.0f : 0.0f; }
      }
      {
        int j = j0 + 3;
        if (j != i) { int e = i*255 + (j < i ? j : j-1);
          Lb[e] = lg3; Kb[e] = (lg3 > 0.f && vi && vj3) ? 1.0f : 0.0f; }
      }
    }
  }
}

extern "C" void kernel_launch(void* const* d_in, const int* in_sizes, int n_in,
                              void* d_out, int out_size, void* d_ws, size_t ws_size,
                              hipStream_t stream) {
  const float* jl    = (const float*)d_in[0];
  const float* off   = (const float*)d_in[1];
  const float* nmap  = (const float*)d_in[2];
  const float* Wself = (const float*)d_in[3];
  const float* Wnbr  = (const float*)d_in[4];
  const float* bg    = (const float*)d_in[5];
  const float* Ws1   = (const float*)d_in[6];
  const float* bs1   = (const float*)d_in[7];
  const float* Ws2   = (const float*)d_in[8];
  const float* bs2   = (const float*)d_in[9];

  char* ws = (char*)d_ws;
  int*   topi    = (int*)  (ws + 0);                 //  4 KiB
  int*   valid   = (int*)  (ws + 4096);              //  4 KiB
  float* inv_deg = (float*)(ws + 8192);              //  4 KiB
  float* Sbuf    = (float*)(ws + 12288);             // 16 KiB (layer colsums)
  unsigned short* xa = (unsigned short*)(ws + 28672);    // 512 KiB bf16
  unsigned short* xb = (unsigned short*)(ws + 552960);   // 512 KiB bf16
  float* u       = (float*)(ws + 1077248);           // 512 KiB fp32
  float* vt      = (float*)(ws + 1601536);           // 512 KiB fp32
  unsigned short* wbfT = (unsigned short*)(ws + 2125824); // 768 KiB transposed bf16
  unsigned short* wuvT = (unsigned short*)(ws + 2912256); // 128 KiB transposed bf16

  float* out        = (float*)d_out;
  float* out_nodes  = out;                  // [4,256,2]   -> 2048
  float* out_emb    = out + 2048;           // [4,256,256] -> 262144
  float* out_logits = out + 264192;         // [4,65280]   -> 261120
  float* out_keep   = out + 525312;         // [4,65280]   -> 261120

  hipLaunchKernelGGL(k_topk,   dim3(BB + 448), dim3(1024), 0, stream,
                     jl, off, topi, valid, inv_deg, out_nodes, Sbuf,
                     Wself, Wnbr, Ws1, wbfT, wuvT);
  hipLaunchKernelGGL(k_gather, dim3(BB*NN),    dim3(256),  0, stream,
                     nmap, topi, valid, xa, Sbuf);

  unsigned short* xc = xa; unsigned short* xn = xb;
  for (int l = 0; l < 3; ++l) {
    hipLaunchKernelGGL(k_gnn, dim3(512), dim3(256),  0, stream,
                       xc, Sbuf + l*BB*CC, inv_deg, valid,
                       wbfT + (size_t)l*65536, wbfT + (size_t)(3 + l)*65536, bg + l*CC,
                       xn,
                       (l < 2) ? (Sbuf + (l+1)*BB*CC) : (float*)nullptr,
                       (l == 2) ? out_emb : (float*)nullptr);
    unsigned short* t = xc; xc = xn; xn = t;
  }

  hipLaunchKernelGGL(k_uv,    dim3(256),   dim3(256), 0, stream, xc, wuvT, bs1, u, vt);
  hipLaunchKernelGGL(k_edges, dim3(BB*64), dim3(256), 0, stream,
                     u, vt, Ws2, bs2, valid, out_logits, out_keep);
}

// Round 17
// 72.417 us; speedup vs baseline: 4.9029x; 1.0621x over previous
//
#include <hip/hip_runtime.h>

#define NPIX 16384   // 128*128
#define NN   256     // max_nodes
#define CC   256     // NFEAT
#define HH   128     // SCORER_HIDDEN
#define EE   65280   // NN*(NN-1)
#define BB   4
#define NG   32      // histogram privatization groups (per half-wave)

typedef __attribute__((ext_vector_type(8))) short short8;   // bf16x8 MFMA frag
typedef __attribute__((ext_vector_type(4))) float f32x4;    // fp32x4 acc

__device__ __forceinline__ unsigned short f2bf(float f){
  unsigned b = __float_as_uint(f);
  return (unsigned short)((b + 0x7fffu + ((b >> 16) & 1u)) >> 16);
}
__device__ __forceinline__ float bf2f(unsigned short s){ return __uint_as_float(((unsigned)s) << 16); }
__device__ __forceinline__ float bf_lo(unsigned u){ return __uint_as_float(u << 16); }
__device__ __forceinline__ float bf_hi(unsigned u){ return __uint_as_float(u & 0xFFFF0000u); }

// ---------------- Kernel 1: top-k (blocks 0..3) + weight bf16 transpose (blocks 4..451) ----
__global__ __launch_bounds__(1024) void k_topk(
    const float* __restrict__ jl, const float* __restrict__ off,
    int* __restrict__ topi, int* __restrict__ valid, float* __restrict__ inv_deg,
    float* __restrict__ out_nodes, float* __restrict__ Sbuf,
    const float* __restrict__ Wself, const float* __restrict__ Wnbr,
    const float* __restrict__ Ws1,
    unsigned short* __restrict__ wbfT, unsigned short* __restrict__ wuvT)
{
  __shared__ int hist[NG][257];        // 32 KiB, 32 private copies
  __shared__ int histT[256];
  __shared__ unsigned long long s_sel[NN];
  __shared__ unsigned long long s_T;
  __shared__ int s_digit, s_krem, s_cnt, s_vcnt, s_break;
  __shared__ float tile[32][33];

  const int bid = blockIdx.x;
  const int tid = threadIdx.x;

  if (bid >= BB) {
    const int blk = bid - BB;            // 0..447
    const int m = blk >> 6;              // 0..6
    const int t = blk & 63;
    const int r  = tid >> 5;             // 0..31
    const int cl = tid & 31;
    if (m < 6) {
      const int tr = t >> 3, tc = t & 7;
      const float* src = (m < 3) ? (Wself + (size_t)m*65536) : (Wnbr + (size_t)(m-3)*65536);
      tile[r][cl] = src[(size_t)(tr*32 + r)*256 + tc*32 + cl];
      __syncthreads();
      wbfT[(size_t)m*65536 + (size_t)(tc*32 + r)*256 + tr*32 + cl] = f2bf(tile[cl][r]);
    } else {
      const int tr = t >> 2, tc = t & 3;   // tr 0..15 (512 rows), tc 0..3 (128 cols)
      tile[r][cl] = Ws1[(size_t)(tr*32 + r)*128 + tc*32 + cl];
      __syncthreads();
      int h  = tc*32 + r;          // 0..127
      int cgx = tr*32 + cl;        // 0..511
      int col = h + ((cgx >= 256) ? 128 : 0);
      wuvT[(size_t)col*256 + (cgx & 255)] = f2bf(tile[cl][r]);
    }
    return;
  }

  const int b = bid;
  const int grp = tid >> 5;            // one private hist per half-wave (32 copies)
  if (tid == 0) { s_cnt = 0; s_vcnt = 0; }

  {
    int l = tid >> 8, c = tid & 255;
    Sbuf[l*BB*CC + b*CC + c] = 0.0f;
  }

  unsigned long long rk[16];
  const float* p = jl + (size_t)b * NPIX;
  #pragma unroll
  for (int r = 0; r < 16; ++r) {
    int i = tid + (r << 10);
    float x = p[i];
    float pr = 1.0f / (1.0f + expf(-x));
    unsigned bits = __float_as_uint(pr);
    rk[r] = ((unsigned long long)bits << 32) | (unsigned)(0xFFFFFFFFu - (unsigned)i);
  }

  unsigned long long prefix = 0;
  int k = NN;
  int shift = 56;
  int brk = 0;
  for (int pass = 0; pass < 8 && !brk; ++pass) {
    shift = 56 - 8 * pass;
    for (int i = tid; i < NG * 257; i += 1024) ((int*)hist)[i] = 0;
    __syncthreads();
    unsigned long long pmask = (pass == 0) ? 0ULL : (~0ULL << (shift + 8));
    #pragma unroll
    for (int r = 0; r < 16; ++r) {
      unsigned long long kk = rk[r];
      if ((kk & pmask) == prefix)
        atomicAdd(&hist[grp][(int)((kk >> shift) & 255)], 1);
    }
    __syncthreads();
    if (tid < 256) {
      int t = 0;
      #pragma unroll
      for (int g = 0; g < NG; ++g) t += hist[g][tid];
      histT[tid] = t;
    }
    __syncthreads();
    if (tid < 64) {
      int h0 = histT[4*tid + 0], h1 = histT[4*tid + 1];
      int h2 = histT[4*tid + 2], h3 = histT[4*tid + 3];
      int tot = h0 + h1 + h2 + h3;
      int suf = tot;
      #pragma unroll
      for (int d = 1; d < 64; d <<= 1) {
        int o = __shfl_down(suf, d);
        if (tid + d < 64) suf += o;
      }
      int above = suf - tot;
      int c3 = h3 + above;
      int c2 = c3 + h2;
      int c1 = c2 + h1;
      int c0 = c1 + h0;
      if      (c3 >= k && above < k) { s_digit = 4*tid+3; s_krem = k - above; s_break = (h3 == 1); }
      else if (c2 >= k && c3    < k) { s_digit = 4*tid+2; s_krem = k - c3;    s_break = (h2 == 1); }
      else if (c1 >= k && c2    < k) { s_digit = 4*tid+1; s_krem = k - c2;    s_break = (h1 == 1); }
      else if (c0 >= k && c1    < k) { s_digit = 4*tid+0; s_krem = k - c1;    s_break = (h0 == 1); }
    }
    __syncthreads();
    prefix |= ((unsigned long long)s_digit) << shift;
    k = s_krem;
    brk = s_break;
  }

  if (shift == 0) {
    if (tid == 0) s_T = prefix;
  } else {
    unsigned long long known_mask = ~0ULL << shift;
    #pragma unroll
    for (int r = 0; r < 16; ++r)
      if ((rk[r] & known_mask) == prefix) s_T = rk[r];
  }
  __syncthreads();
  unsigned long long T = s_T;

  #pragma unroll
  for (int r = 0; r < 16; ++r) {
    unsigned long long kk = rk[r];
    if (kk >= T) { int pos = atomicAdd(&s_cnt, 1); s_sel[pos] = kk; }
  }
  __syncthreads();

  int my_rank = -1, my_v = 0;
  if (tid < NN) {
    unsigned long long mine = s_sel[tid];
    int rank = 0;
    #pragma unroll 16
    for (int j = 0; j < NN; ++j) rank += (s_sel[j] > mine) ? 1 : 0;
    unsigned bits = (unsigned)(mine >> 32);
    int v = bits > 0x3F000000u ? 1 : 0;
    int idx = (int)(0xFFFFFFFFu - (unsigned)(mine & 0xFFFFFFFFull));
    if (v) atomicAdd(&s_vcnt, 1);
    topi[b*NN + rank] = idx;
    valid[b*NN + rank] = v;
    int iy = idx >> 7;
    int ix = idx & 127;
    float yo = off[((size_t)b*2 + 0) * NPIX + idx];
    float xo = off[((size_t)b*2 + 1) * NPIX + idx];
    out_nodes[(b*NN + rank)*2 + 0] = ((float)ix + 0.5f + xo) * 4.0f;
    out_nodes[(b*NN + rank)*2 + 1] = ((float)iy + 0.5f + yo) * 4.0f;
    my_rank = rank; my_v = v;
  }
  __syncthreads();
  if (tid < NN) {
    int V = s_vcnt;
    inv_deg[b*NN + my_rank] = (my_v && V >= 2) ? 1.0f / (float)(V - 1) : 0.0f;
  }
}

// ---------------- Kernel 2: gather (8 nodes/block-row) + private colsum, 1 atomic/thread ----
// Grid 128 = 4 images x 32 node-groups. Thread c accumulates its column over 8 nodes.
__global__ __launch_bounds__(256) void k_gather(
    const float* __restrict__ nmap, const int* __restrict__ topi,
    const int* __restrict__ valid, unsigned short* __restrict__ x, float* __restrict__ S0)
{
  __shared__ int s_pix[8], s_val[8];
  const int blk = blockIdx.x;
  const int b  = blk >> 5;
  const int n0 = (blk & 31) * 8;
  const int c = threadIdx.x;
  if (c < 8) { s_pix[c] = topi[b*NN + n0 + c]; s_val[c] = valid[b*NN + n0 + c]; }
  __syncthreads();
  const float* base = nmap + ((size_t)b*CC + c) * NPIX;
  float sum = 0.f;
  #pragma unroll
  for (int r = 0; r < 8; ++r) {
    float val = s_val[r] ? base[s_pix[r]] : 0.0f;
    unsigned short hb = f2bf(val);
    x[(size_t)(b*NN + n0 + r)*CC + c] = hb;
    sum += bf2f(hb);
  }
  if (sum != 0.0f) atomicAdd(&S0[b*CC + c], sum);
}

// ---------------- Kernel 3: GNN layer via MFMA, P2 fused in-block (vectorized) ----------------
__global__ __launch_bounds__(256) void k_gnn(
    const unsigned short* __restrict__ x, const float* __restrict__ S,
    const float* __restrict__ inv_deg, const int* __restrict__ valid,
    const unsigned short* __restrict__ wT1, const unsigned short* __restrict__ wT2,
    const float* __restrict__ bias, unsigned short* __restrict__ xout,
    float* __restrict__ Snext,     // may be null
    float* __restrict__ out_emb)   // may be null
{
  __shared__ float sA1[16][33];
  __shared__ float sA2[16][33];
  __shared__ float sP2p[8][33];
  __shared__ float sP2[32];
  const int mt = blockIdx.x >> 3;            // 0..63
  const int cg = blockIdx.x & 7;             // 0..7
  const int row0 = mt * 16;
  const int b = row0 >> 8;
  const int tid = threadIdx.x;
  const int wave = tid >> 6;
  const int lane = tid & 63;

  // ---- P2 slice: P2[cg*32 + cl] = sum_c S[c] * wT2[col][c], uint4/float4 loads ----
  {
    const int cl = tid >> 3;         // 0..31
    const int kw = tid & 7;          // 0..7, 32 c's each
    const uint4*  w4 = (const uint4*)(wT2 + (size_t)(cg*32 + cl)*256 + kw*32);
    const float4* S4 = (const float4*)(S + b*CC + kw*32);
    float a = 0.f;
    #pragma unroll
    for (int i = 0; i < 4; ++i) {
      uint4 q = w4[i];
      float4 s0 = S4[2*i], s1 = S4[2*i + 1];
      a += s0.x*bf_lo(q.x) + s0.y*bf_hi(q.x) + s0.z*bf_lo(q.y) + s0.w*bf_hi(q.y);
      a += s1.x*bf_lo(q.z) + s1.y*bf_hi(q.z) + s1.z*bf_lo(q.w) + s1.w*bf_hi(q.w);
    }
    sP2p[kw][cl] = a;
  }
  __syncthreads();
  if (tid < 32) {
    float s = 0.f;
    #pragma unroll
    for (int g = 0; g < 8; ++g) s += sP2p[g][tid];
    sP2[tid] = s;
  }

  // ---- MFMA GEMM ----
  const unsigned short* wT = (wave < 2) ? wT1 : wT2;
  const int colbase = cg*32 + (wave & 1)*16;
  const int arow = row0 + (lane & 15);
  const int koff = (lane >> 4) * 8;

  const short8* aptr = (const short8*)(x + (size_t)arow*256 + koff);
  const short8* bptr = (const short8*)(wT + (size_t)(colbase + (lane & 15))*256 + koff);

  f32x4 acc = {0.f, 0.f, 0.f, 0.f};
  #pragma unroll
  for (int kk = 0; kk < 8; ++kk) {
    short8 af = aptr[kk*4];      // advance 32 bf16 per chunk
    short8 bf = bptr[kk*4];
    acc = __builtin_amdgcn_mfma_f32_16x16x32_bf16(af, bf, acc, 0, 0, 0);
  }

  {
    float* dst = (wave < 2) ? &sA1[0][0] : &sA2[0][0];
    int ccol = (wave & 1)*16 + (lane & 15);
    #pragma unroll
    for (int r = 0; r < 4; ++r) {
      int crow = (lane >> 4)*4 + r;
      dst[crow*33 + ccol] = acc[r];
    }
  }
  __syncthreads();

  // epilogue: thread t -> row = t>>4, colpair cp2 = t&15
  const int row = tid >> 4;
  const int cp2 = tid & 15;
  const int gr = row0 + row;
  const int c0 = cg*32 + 2*cp2;
  float inv = inv_deg[gr];
  int   va  = valid[gr];
  float a10 = sA1[row][2*cp2], a11 = sA1[row][2*cp2+1];
  float a20 = sA2[row][2*cp2], a21 = sA2[row][2*cp2+1];
  float p0 = sP2[2*cp2], p1 = sP2[2*cp2+1];
  float o0 = fmaxf(a10 + inv*(p0 - a20) + bias[c0],     0.f); o0 = va ? o0 : 0.f;
  float o1 = fmaxf(a11 + inv*(p1 - a21) + bias[c0 + 1], 0.f); o1 = va ? o1 : 0.f;

  unsigned short h0 = f2bf(o0), h1 = f2bf(o1);
  ((unsigned*)xout)[(size_t)gr*128 + (cg*16 + cp2)] = (unsigned)h0 | ((unsigned)h1 << 16);
  if (out_emb) {
    float2 v; v.x = o0; v.y = o1;
    *(float2*)&out_emb[(size_t)gr*CC + c0] = v;
  }
  if (Snext) {
    __syncthreads();                 // all sA1 reads done
    sA1[row][2*cp2]   = bf2f(h0);    // colsum of rounded values (matches next layer's x)
    sA1[row][2*cp2+1] = bf2f(h1);
    __syncthreads();
    if (tid < 32) {
      float s = 0.f;
      #pragma unroll
      for (int r = 0; r < 16; ++r) s += sA1[r][tid];
      if (s != 0.f) atomicAdd(&Snext[b*CC + cg*32 + tid], s);
    }
  }
}

// ---------------- Kernel 4: u/vt via MFMA; bs1 folded into u ----------------
__global__ __launch_bounds__(256) void k_uv(
    const unsigned short* __restrict__ x, const unsigned short* __restrict__ wuvT,
    const float* __restrict__ bs1,
    float* __restrict__ u, float* __restrict__ vt)
{
  const int mt = blockIdx.x >> 2;      // 0..63
  const int cg = blockIdx.x & 3;       // 0..3 (64 cols each)
  const int row0 = mt * 16;
  const int b = row0 >> 8;
  const int wave = threadIdx.x >> 6;
  const int lane = threadIdx.x & 63;
  const int col = cg*64 + wave*16 + (lane & 15);
  const int arow = row0 + (lane & 15);
  const int koff = (lane >> 4) * 8;
  const short8* aptr = (const short8*)(x + (size_t)arow*256 + koff);
  const short8* bptr = (const short8*)(wuvT + (size_t)col*256 + koff);
  f32x4 acc = {0.f, 0.f, 0.f, 0.f};
  #pragma unroll
  for (int kk = 0; kk < 8; ++kk)
    acc = __builtin_amdgcn_mfma_f32_16x16x32_bf16(aptr[kk*4], bptr[kk*4], acc, 0, 0, 0);
  const int rbase = row0 + (lane >> 4)*4;
  if (col < HH) {
    float bv = bs1[col];
    #pragma unroll
    for (int r = 0; r < 4; ++r)
      u[(size_t)(rbase + r)*HH + col] = acc[r] + bv;
  } else {
    float4 v; v.x = acc[0]; v.y = acc[1]; v.z = acc[2]; v.w = acc[3];
    *(float4*)&vt[(size_t)(b*HH + (col - HH))*NN + rbase] = v;
  }
}

// ---------------- Kernel 5: per-edge scorer, 4 src nodes per block ----------------
__global__ __launch_bounds__(256) void k_edges(
    const float* __restrict__ u, const float* __restrict__ vt,
    const float* __restrict__ Ws2, const float* __restrict__ bs2,
    const int* __restrict__ valid,
    float* __restrict__ out_logits, float* __restrict__ out_keep)
{
  __shared__ float su[4][HH];          // 2 KiB   u rows (bs1 already folded)
  __shared__ float sws[HH];            // 0.5 KiB Ws2
  __shared__ float4 red[3][4][64];     // 12 KiB  partial sums
  const int b  = blockIdx.x >> 6;
  const int ig = blockIdx.x & 63;
  const int i0 = ig * 4;
  const int tid = threadIdx.x;
  const int jq = tid & 63;
  const int kh = tid >> 6;             // h-partition 0..3 (32 h each)

  #pragma unroll
  for (int r = 0; r < 2; ++r) {
    int idx = tid + 256*r;             // 0..511
    int il = idx >> 7, h = idx & 127;
    su[il][h] = u[((size_t)(b*NN + i0 + il))*HH + h];
  }
  if (tid < HH) sws[tid] = Ws2[tid];
  __syncthreads();

  const float4* vbase = (const float4*)(vt + (size_t)(b*HH + kh*32)*NN) + jq;
  float4 acc0 = {0,0,0,0}, acc1 = {0,0,0,0}, acc2 = {0,0,0,0}, acc3 = {0,0,0,0};
  #pragma unroll 4
  for (int h = 0; h < 32; ++h) {
    float4 v = vbase[(size_t)h*64];
    float wh = sws[kh*32 + h];
    float u0 = su[0][kh*32 + h];
    float u1 = su[1][kh*32 + h];
    float u2 = su[2][kh*32 + h];
    float u3 = su[3][kh*32 + h];
    acc0.x += fmaxf(u0 + v.x, 0.f)*wh; acc0.y += fmaxf(u0 + v.y, 0.f)*wh;
    acc0.z += fmaxf(u0 + v.z, 0.f)*wh; acc0.w += fmaxf(u0 + v.w, 0.f)*wh;
    acc1.x += fmaxf(u1 + v.x, 0.f)*wh; acc1.y += fmaxf(u1 + v.y, 0.f)*wh;
    acc1.z += fmaxf(u1 + v.z, 0.f)*wh; acc1.w += fmaxf(u1 + v.w, 0.f)*wh;
    acc2.x += fmaxf(u2 + v.x, 0.f)*wh; acc2.y += fmaxf(u2 + v.y, 0.f)*wh;
    acc2.z += fmaxf(u2 + v.z, 0.f)*wh; acc2.w += fmaxf(u2 + v.w, 0.f)*wh;
    acc3.x += fmaxf(u3 + v.x, 0.f)*wh; acc3.y += fmaxf(u3 + v.y, 0.f)*wh;
    acc3.z += fmaxf(u3 + v.z, 0.f)*wh; acc3.w += fmaxf(u3 + v.w, 0.f)*wh;
  }
  if (kh > 0) {
    red[kh-1][0][jq] = acc0;
    red[kh-1][1][jq] = acc1;
    red[kh-1][2][jq] = acc2;
    red[kh-1][3][jq] = acc3;
  }
  __syncthreads();
  if (kh == 0) {
    float bs = bs2[0];
    float* Lb = out_logits + (size_t)b*EE;
    float* Kb = out_keep   + (size_t)b*EE;
    int j0 = 4*jq;
    int vj0 = valid[b*NN + j0 + 0];
    int vj1 = valid[b*NN + j0 + 1];
    int vj2 = valid[b*NN + j0 + 2];
    int vj3 = valid[b*NN + j0 + 3];
    #pragma unroll
    for (int il = 0; il < 4; ++il) {
      int i = i0 + il;
      int vi = valid[b*NN + i];
      float4 a = (il == 0) ? acc0 : (il == 1) ? acc1 : (il == 2) ? acc2 : acc3;
      float4 r0 = red[0][il][jq], r1 = red[1][il][jq], r2 = red[2][il][jq];
      float lg0 = a.x + r0.x + r1.x + r2.x + bs;
      float lg1 = a.y + r0.y + r1.y + r2.y + bs;
      float lg2 = a.z + r0.z + r1.z + r2.z + bs;
      float lg3 = a.w + r0.w + r1.w + r2.w + bs;
      {
        int j = j0;
        if (j != i) { int e = i*255 + (j < i ? j : j-1);
          Lb[e] = lg0; Kb[e] = (lg0 > 0.f && vi && vj0) ? 1.0f : 0.0f; }
      }
      {
        int j = j0 + 1;
        if (j != i) { int e = i*255 + (j < i ? j : j-1);
          Lb[e] = lg1; Kb[e] = (lg1 > 0.f && vi && vj1) ? 1.0f : 0.0f; }
      }
      {
        int j = j0 + 2;
        if (j != i) { int e = i*255 + (j < i ? j : j-1);
          Lb[e] = lg2; Kb[e] = (lg2 > 0.f && vi && vj2) ? 1.0f : 0.0f; }
      }
      {
        int j = j0 + 3;
        if (j != i) { int e = i*255 + (j < i ? j : j-1);
          Lb[e] = lg3; Kb[e] = (lg3 > 0.f && vi && vj3) ? 1.0f : 0.0f; }
      }
    }
  }
}

extern "C" void kernel_launch(void* const* d_in, const int* in_sizes, int n_in,
                              void* d_out, int out_size, void* d_ws, size_t ws_size,
                              hipStream_t stream) {
  const float* jl    = (const float*)d_in[0];
  const float* off   = (const float*)d_in[1];
  const float* nmap  = (const float*)d_in[2];
  const float* Wself = (const float*)d_in[3];
  const float* Wnbr  = (const float*)d_in[4];
  const float* bg    = (const float*)d_in[5];
  const float* Ws1   = (const float*)d_in[6];
  const float* bs1   = (const float*)d_in[7];
  const float* Ws2   = (const float*)d_in[8];
  const float* bs2   = (const float*)d_in[9];

  char* ws = (char*)d_ws;
  int*   topi    = (int*)  (ws + 0);                 //  4 KiB
  int*   valid   = (int*)  (ws + 4096);              //  4 KiB
  float* inv_deg = (float*)(ws + 8192);              //  4 KiB
  float* Sbuf    = (float*)(ws + 12288);             // 16 KiB (layer colsums)
  unsigned short* xa = (unsigned short*)(ws + 28672);    // 512 KiB bf16
  unsigned short* xb = (unsigned short*)(ws + 552960);   // 512 KiB bf16
  float* u       = (float*)(ws + 1077248);           // 512 KiB fp32
  float* vt      = (float*)(ws + 1601536);           // 512 KiB fp32
  unsigned short* wbfT = (unsigned short*)(ws + 2125824); // 768 KiB transposed bf16
  unsigned short* wuvT = (unsigned short*)(ws + 2912256); // 128 KiB transposed bf16

  float* out        = (float*)d_out;
  float* out_nodes  = out;                  // [4,256,2]   -> 2048
  float* out_emb    = out + 2048;           // [4,256,256] -> 262144
  float* out_logits = out + 264192;         // [4,65280]   -> 261120
  float* out_keep   = out + 525312;         // [4,65280]   -> 261120

  hipLaunchKernelGGL(k_topk,   dim3(BB + 448), dim3(1024), 0, stream,
                     jl, off, topi, valid, inv_deg, out_nodes, Sbuf,
                     Wself, Wnbr, Ws1, wbfT, wuvT);
  hipLaunchKernelGGL(k_gather, dim3(BB*32),    dim3(256),  0, stream,
                     nmap, topi, valid, xa, Sbuf);

  unsigned short* xc = xa; unsigned short* xn = xb;
  for (int l = 0; l < 3; ++l) {
    hipLaunchKernelGGL(k_gnn, dim3(512), dim3(256),  0, stream,
                       xc, Sbuf + l*BB*CC, inv_deg, valid,
                       wbfT + (size_t)l*65536, wbfT + (size_t)(3 + l)*65536, bg + l*CC,
                       xn,
                       (l < 2) ? (Sbuf + (l+1)*BB*CC) : (float*)nullptr,
                       (l == 2) ? out_emb : (float*)nullptr);
    unsigned short* t = xc; xc = xn; xn = t;
  }

  hipLaunchKernelGGL(k_uv,    dim3(256),   dim3(256), 0, stream, xc, wuvT, bs1, u, vt);
  hipLaunchKernelGGL(k_edges, dim3(BB*64), dim3(256), 0, stream,
                     u, vt, Ws2, bs2, valid, out_logits, out_keep);
}